// Round 1
// baseline (731.848 us; speedup 1.0000x reference)
//
#include <hip/hip_runtime.h>
#include <cmath>

#define Bsz   128
#define INsz  1024
#define OUTsz 1024
#define ZDsz  128

typedef __bf16 bf16x8 __attribute__((ext_vector_type(8)));
typedef __bf16 bf16x4 __attribute__((ext_vector_type(4)));
typedef float  floatx4 __attribute__((ext_vector_type(4)));

// ---------------------------------------------------------------------------
// Single fused kernel, R4.
//   P[i,b]      = sum_z dwW[o,i,z] * z[b,z]          (bf16 MFMA 16x16x32, A=dwW, B=z^T)
//   w_extra[i]  = dwb[o,i] + (a/(1-a))*W[o,i]        (fp32, b-independent)
//   oacc[o,b]  += sum_i (P[i,b]+w_extra[i]) * x[b,i] (x from LDS as bf16)
//   (y==0 only) oacc[o,b] += (z.dbW^T)[b,o] + ratio*bb[o] + dbb[o]
//   out[b,o]   += (1-a) * oacc[o,b]                  (atomicAdd; out pre-zeroed)
// grid (64 o-tiles, 8 i-splits) x 256 thr = 512 blocks = 2 blocks/CU.
// R4 change vs R3: host-side only. rocprof showed the timed region was
// dominated by a 2 GiB fillBufferAligned (~333 us @ 6.4 TB/s): out_size from
// the harness is ~2^29, but the checked output is only B*OUT = 131072 floats.
// We now memset exactly B*OUT*4 = 512 KB (the only region the flush
// atomicAdds into). Kernel body unchanged — it is ~HBM-bound on the 512 MB
// dwW stream (roofline ~82 us @ 6.3 TB/s).
// ---------------------------------------------------------------------------
__global__ __launch_bounds__(256, 2) void hyper_fused_kernel(
    const float* __restrict__ x, const float* __restrict__ z,
    const float* __restrict__ W, const float* __restrict__ dwW,
    const float* __restrict__ dwb, const float* __restrict__ bb,
    const float* __restrict__ dbW, const float* __restrict__ dbb,
    const float* __restrict__ s, float* __restrict__ out)
{
    __shared__ __align__(16) __bf16 smem[128 * 136];  // z (phase 1) then x-tile (phase 2)
    __shared__ float oacc[16 * 128];                  // [o_local][b] fp32 accumulator

    int t    = threadIdx.x;
    int lane = t & 63;
    int wave = t >> 6;
    int quad = lane >> 4;
    int l15  = lane & 15;
    int l31  = lane & 31;
    int rowp = lane >> 5;

    float a     = 0.2f / (1.f + __expf(-s[0]));
    float one_a = 1.f - a;
    float ratio = a / one_a;

    int otile = blockIdx.x * 16;
    int ibase = blockIdx.y * 128;

    // ---- phase 1: stage z -> smem (bf16), coalesced: 2 rows x 512B per instr
    #pragma unroll
    for (int j = 0; j < 16; ++j) {
        int r  = wave * 32 + 2 * j + rowp;
        int cc = l31 * 4;
        float4 v = *reinterpret_cast<const float4*>(z + (size_t)r * ZDsz + cc);
        __bf16* d = &smem[r * 136 + cc];
        d[0] = (__bf16)v.x; d[1] = (__bf16)v.y; d[2] = (__bf16)v.z; d[3] = (__bf16)v.w;
    }
    #pragma unroll
    for (int j = 0; j < 8; ++j) oacc[t * 8 + j] = 0.f;
    __syncthreads();

    // resident B-fragments: B[k=z][n=b] = z[b,z]; frag: n=lane&15, k=quad*8+j
    bf16x8 bfrag[8][4];
    #pragma unroll
    for (int sj = 0; sj < 8; ++sj)
        #pragma unroll
        for (int k = 0; k < 4; ++k)
            bfrag[sj][k] = *reinterpret_cast<const bf16x8*>(
                &smem[(sj * 16 + l15) * 136 + k * 32 + quad * 8]);
    __syncthreads();   // bfrag reg-loads complete before smem is overwritten

    // ---- phase 2: stage x-tile (this block's 128 i-cols) -> smem (bf16)
    #pragma unroll
    for (int j = 0; j < 16; ++j) {
        int r  = wave * 32 + 2 * j + rowp;
        int cc = l31 * 4;
        float4 v = *reinterpret_cast<const float4*>(x + (size_t)r * INsz + ibase + cc);
        __bf16* d = &smem[r * 136 + cc];
        d[0] = (__bf16)v.x; d[1] = (__bf16)v.y; d[2] = (__bf16)v.z; d[3] = (__bf16)v.w;
    }
    __syncthreads();

    // ---- prefetched A-stream state
    float4 avlo[4], avhi[4], Wv, Dv;
    auto load_iter = [&](int idx) {
        int it = idx >> 2, c = idx & 3;
        int i0 = ibase + it * 16;
        int o  = otile + wave * 4 + c;
        const float* ab = dwW + ((size_t)o * INsz + i0 + l15) * ZDsz + quad * 8;
        #pragma unroll
        for (int k = 0; k < 4; ++k) {
            avlo[k] = *reinterpret_cast<const float4*>(ab + k * 32);
            avhi[k] = *reinterpret_cast<const float4*>(ab + k * 32 + 4);
        }
        Wv = *reinterpret_cast<const float4*>(W   + (size_t)o * INsz + i0 + quad * 4);
        Dv = *reinterpret_cast<const float4*>(dwb + (size_t)o * INsz + i0 + quad * 4);
    };
    load_iter(0);

    // ---- barrier-free K-loop: 32 flat iterations (8 i-steps x 4 o-per-wave)
    #pragma unroll 1
    for (int idx = 0; idx < 32; ++idx) {
        int it = idx >> 2, c = idx & 3;

        // consume prefetched data -> afrag / wex
        bf16x8 afrag[4];
        #pragma unroll
        for (int k = 0; k < 4; ++k) {
            afrag[k][0]=(__bf16)avlo[k].x; afrag[k][1]=(__bf16)avlo[k].y;
            afrag[k][2]=(__bf16)avlo[k].z; afrag[k][3]=(__bf16)avlo[k].w;
            afrag[k][4]=(__bf16)avhi[k].x; afrag[k][5]=(__bf16)avhi[k].y;
            afrag[k][6]=(__bf16)avhi[k].z; afrag[k][7]=(__bf16)avhi[k].w;
        }
        float wex0 = Dv.x + ratio * Wv.x;
        float wex1 = Dv.y + ratio * Wv.y;
        float wex2 = Dv.z + ratio * Wv.z;
        float wex3 = Dv.w + ratio * Wv.w;

        if (idx < 31) load_iter(idx + 1);   // overlap next A-stream with MFMA+epilogue

        #pragma unroll
        for (int sj = 0; sj < 8; ++sj) {
            floatx4 cf = {0.f, 0.f, 0.f, 0.f};
            #pragma unroll
            for (int k = 0; k < 4; ++k)
                cf = __builtin_amdgcn_mfma_f32_16x16x32_bf16(afrag[k], bfrag[sj][k], cf, 0, 0, 0);
            // x[b=sj*16+l15, ibase + it*16 + quad*4 + r] from LDS (bf16, 8B read)
            bf16x4 xr = *reinterpret_cast<const bf16x4*>(
                &smem[(sj * 16 + l15) * 136 + it * 16 + quad * 4]);
            float p = (cf[0] + wex0) * (float)xr[0] + (cf[1] + wex1) * (float)xr[1]
                    + (cf[2] + wex2) * (float)xr[2] + (cf[3] + wex3) * (float)xr[3];
            p += __shfl_xor(p, 16);
            p += __shfl_xor(p, 32);
            if (lane < 16) oacc[(wave * 4 + c) * 128 + sj * 16 + l15] += p;
        }
    }

    // ---- dbW MFMA + bias (only the y==0 i-split blocks contribute these)
    if (blockIdx.y == 0) {
        __syncthreads();
        const float* ab = dbW + (size_t)(otile + l15) * ZDsz + quad * 8;
        bf16x8 afrag[4];
        #pragma unroll
        for (int k = 0; k < 4; ++k) {
            float4 lo = *reinterpret_cast<const float4*>(ab + k * 32);
            float4 hi = *reinterpret_cast<const float4*>(ab + k * 32 + 4);
            afrag[k][0]=(__bf16)lo.x; afrag[k][1]=(__bf16)lo.y;
            afrag[k][2]=(__bf16)lo.z; afrag[k][3]=(__bf16)lo.w;
            afrag[k][4]=(__bf16)hi.x; afrag[k][5]=(__bf16)hi.y;
            afrag[k][6]=(__bf16)hi.z; afrag[k][7]=(__bf16)hi.w;
        }
        float4 bbv  = *reinterpret_cast<const float4*>(bb  + otile + quad * 4);
        float4 dbbv = *reinterpret_cast<const float4*>(dbb + otile + quad * 4);
        float bias0 = ratio * bbv.x + dbbv.x, bias1 = ratio * bbv.y + dbbv.y;
        float bias2 = ratio * bbv.z + dbbv.z, bias3 = ratio * bbv.w + dbbv.w;
        #pragma unroll
        for (int u = 0; u < 2; ++u) {
            int sj = wave * 2 + u;
            floatx4 cf = {0.f, 0.f, 0.f, 0.f};
            #pragma unroll
            for (int k = 0; k < 4; ++k)
                cf = __builtin_amdgcn_mfma_f32_16x16x32_bf16(afrag[k], bfrag[sj][k], cf, 0, 0, 0);
            oacc[(quad * 4 + 0) * 128 + sj * 16 + l15] += cf[0] + bias0;
            oacc[(quad * 4 + 1) * 128 + sj * 16 + l15] += cf[1] + bias1;
            oacc[(quad * 4 + 2) * 128 + sj * 16 + l15] += cf[2] + bias2;
            oacc[(quad * 4 + 3) * 128 + sj * 16 + l15] += cf[3] + bias3;
        }
    }
    __syncthreads();

    // ---- flush: 8 i-split blocks add into out (pre-zeroed by memset)
    {
        int b  = t >> 1;
        int og = (t & 1) * 8;
        #pragma unroll
        for (int j = 0; j < 8; ++j)
            atomicAdd(&out[(size_t)b * OUTsz + otile + og + j],
                      one_a * oacc[(og + j) * 128 + b]);
    }
}

extern "C" void kernel_launch(void* const* d_in, const int* in_sizes, int n_in,
                              void* d_out, int out_size, void* d_ws, size_t ws_size,
                              hipStream_t stream) {
    (void)in_sizes; (void)n_in; (void)d_ws; (void)ws_size; (void)out_size;
    const float* x   = (const float*)d_in[0];
    const float* z   = (const float*)d_in[1];
    const float* W   = (const float*)d_in[2];
    const float* dwW = (const float*)d_in[3];
    const float* dwb = (const float*)d_in[4];
    const float* bb  = (const float*)d_in[5];
    const float* dbW = (const float*)d_in[6];
    const float* dbb = (const float*)d_in[7];
    const float* s   = (const float*)d_in[8];
    float* out = (float*)d_out;

    // R4: zero ONLY the checked/accumulated region [B, OUT] = 512 KB.
    // (out_size from the harness is vastly larger; memsetting out_size*4
    // bytes was a 2 GiB / ~333 us fill dominating the timed region.)
    hipMemsetAsync(out, 0, (size_t)Bsz * OUTsz * sizeof(float), stream);
    hyper_fused_kernel<<<dim3(OUTsz / 16, 8), 256, 0, stream>>>(
        x, z, W, dwW, dwb, bb, dbW, dbb, s, out);
}